// Round 8
// baseline (411.015 us; speedup 1.0000x reference)
//
#include <hip/hip_runtime.h>

#define POOL_SHIFT 2
#define GRID_DIM 64
#define NUM_CELLS 4096
#define NCH 64
#define BATCH 64
#define QCS 16                      // 16 channel-quads of 4 channels
#define SENTINEL ((int)0x80000000)  // maps to no real float (only NaN)

typedef float vf4 __attribute__((ext_vector_type(4)));

// ---- K0: batch row ranges (batch is sorted) ----
__global__ __launch_bounds__(256) void bounds_kernel(
    const int* __restrict__ batch, int* __restrict__ bstart, int n) {
    int p = blockIdx.x * blockDim.x + threadIdx.x;
    if (p >= n) return;
    int b = batch[p];
    if (p == 0) {
        for (int i = 0; i <= b; ++i) bstart[i] = 0;
    } else {
        int pb = batch[p - 1];
        for (int i = pb + 1; i <= b; ++i) bstart[i] = p;
    }
    if (p == n - 1) {
        for (int i = b + 1; i <= BATCH; ++i) bstart[i] = n;
    }
}

// order-preserving float->int map (finite floats; inputs have no NaN)
__device__ __forceinline__ int fmap(float f) {
    int i = __float_as_int(f);
    return i >= 0 ? i : (i ^ 0x7fffffff);
}
__device__ __forceinline__ float funmap(int m) {
    if (m == SENTINEL) return 0.0f;              // empty cell -> 0 (ref semantics)
    return __int_as_float(m >= 0 ? m : (m ^ 0x7fffffff));
}

__device__ __forceinline__ void accum(int* acc, int2 pp, vf4 v) {
    int c = ((pp.x >> POOL_SHIFT) << 6) | (pp.y >> POOL_SHIFT);
    // plane-major acc[j][c]: bank = c & 31 (4096 % 32 == 0) -> ~2-way, free
    atomicMax(&acc[0 * NUM_CELLS + c], fmap(v.x));
    atomicMax(&acc[1 * NUM_CELLS + c], fmap(v.y));
    atomicMax(&acc[2 * NUM_CELLS + c], fmap(v.z));
    atomicMax(&acc[3 * NUM_CELLS + c], fmap(v.w));
}

// ---- K1: persistent (batch-pair, channel-quad) workgroups ----
// Grid = 512 = 2 WGs/CU: ALL blocks co-resident in one scheduling round,
// so the 16 sibling WGs of each batch (same b, different qc) provably run
// in lockstep on one XCD (L = grp*128 + qc*8 + xcd keeps L%8 fixed per
// batch under the round-robin block->XCD mapping). Each sibling reads a
// 16-B slice of every 256-B x row; lockstep co-residency lets the XCD L2
// merge the 4 quads sharing each 64-B sector -> x fetched from HBM once.
// Each WG then handles batch b0 and b0+32 sequentially (identical row
// ranges across siblings -> lockstep preserved through both halves).
__global__ __launch_bounds__(256, 2) void pool_kernel(
    const float* __restrict__ x, const int* __restrict__ pos,
    const int* __restrict__ bstart, float* __restrict__ out) {
    __shared__ int acc[4 * NUM_CELLS];   // 64 KB, plane-major [j][cell]
    const int L   = (int)blockIdx.x;
    const int xcd = L & 7;
    const int qc  = (L >> 3) & 15;
    const int grp = L >> 7;              // 0..3
    const int b0  = grp * 8 + xcd;       // 0..31
    const int t   = threadIdx.x;

    const vf4* xq  = (const vf4*)x;      // row r, quad qc -> xq[r*16 + qc]
    const int2* pq = (const int2*)pos;

    for (int half = 0; half < 2; ++half) {
        const int b = b0 + 32 * half;

        for (int i = t; i < 4 * NUM_CELLS; i += 256) acc[i] = SENTINEL;
        __syncthreads();

        const int r0 = bstart[b], r1 = bstart[b + 1];

        int r = r0 + t;
        // 4 independent row-loads in flight per lane
        for (; r + 768 < r1; r += 1024) {
            int2 pp0 = pq[r];
            int2 pp1 = pq[r + 256];
            int2 pp2 = pq[r + 512];
            int2 pp3 = pq[r + 768];
            vf4 v0 = xq[(size_t)r * QCS + qc];
            vf4 v1 = xq[(size_t)(r + 256) * QCS + qc];
            vf4 v2 = xq[(size_t)(r + 512) * QCS + qc];
            vf4 v3 = xq[(size_t)(r + 768) * QCS + qc];
            accum(acc, pp0, v0);
            accum(acc, pp1, v1);
            accum(acc, pp2, v2);
            accum(acc, pp3, v3);
        }
        for (; r < r1; r += 256) {
            int2 pp = pq[r];
            vf4 v = xq[(size_t)r * QCS + qc];
            accum(acc, pp, v);
        }
        __syncthreads();

        // flush: channels qc*4 .. qc*4+3 of every cell of batch b
        const size_t obase = (size_t)b * NUM_CELLS * NCH + (size_t)qc * 4;
        for (int c = t; c < NUM_CELLS; c += 256) {
            vf4 o;
            o.x = funmap(acc[0 * NUM_CELLS + c]);
            o.y = funmap(acc[1 * NUM_CELLS + c]);
            o.z = funmap(acc[2 * NUM_CELLS + c]);
            o.w = funmap(acc[3 * NUM_CELLS + c]);
            *(vf4*)&out[obase + (size_t)c * NCH] = o;  // L2 merges quad-siblings
        }
        __syncthreads();   // flush reads acc before next half re-inits
    }
}

extern "C" void kernel_launch(void* const* d_in, const int* in_sizes, int n_in,
                              void* d_out, int out_size, void* d_ws, size_t ws_size,
                              hipStream_t stream) {
    const float* x   = (const float*)d_in[0];
    const int* pos   = (const int*)d_in[1];
    const int* batch = (const int*)d_in[2];
    float* out = (float*)d_out;
    int n = in_sizes[2];

    int* bstart = (int*)d_ws;           // BATCH + 1 ints

    bounds_kernel<<<(n + 255) / 256, 256, 0, stream>>>(batch, bstart, n);
    pool_kernel<<<512, 256, 0, stream>>>(x, pos, bstart, out);
}